// Round 1
// baseline (184.979 us; speedup 1.0000x reference)
//
#include <hip/hip_runtime.h>
#include <hip/hip_bf16.h>
#include <math.h>

#define CB_M 64      // codewords
#define CB_D 16      // vector dim
#define HARDNESS 5.0f

__global__ __launch_bounds__(256) void stq_kernel(const float* __restrict__ x,
                                                  const float* __restrict__ ref,
                                                  float* __restrict__ out,
                                                  int nvec) {
    // Codebook in LDS as float4 rows: sref[m*4 + j] is ref[m][4j..4j+3]
    __shared__ float4 sref[CB_M * 4];
    __shared__ float  sbias[CB_M];   // -H * ||r_m||^2

    const int tid = threadIdx.x;
    if (tid < CB_M * 4) {
        sref[tid] = ((const float4*)ref)[tid];
    }
    __syncthreads();
    if (tid < CB_M) {
        float4 a = sref[tid * 4 + 0];
        float4 b = sref[tid * 4 + 1];
        float4 c = sref[tid * 4 + 2];
        float4 d = sref[tid * 4 + 3];
        float r2 = a.x*a.x + a.y*a.y + a.z*a.z + a.w*a.w
                 + b.x*b.x + b.y*b.y + b.z*b.z + b.w*b.w
                 + c.x*c.x + c.y*c.y + c.z*c.z + c.w*c.w
                 + d.x*d.x + d.y*d.y + d.z*d.z + d.w*d.w;
        sbias[tid] = -HARDNESS * r2;
    }
    __syncthreads();

    const int i = blockIdx.x * blockDim.x + tid;
    if (i >= nvec) return;

    const float4* xp = (const float4*)(x + (size_t)i * CB_D);
    float4 x0 = xp[0], x1 = xp[1], x2 = xp[2], x3 = xp[3];

    // Pass 1: t_m = 2H * (x . r_m) - H * ||r_m||^2  (x^2 term cancels in softmax)
    float t[CB_M];
    float tmax = -INFINITY;
#pragma unroll
    for (int m = 0; m < CB_M; ++m) {
        float4 r0 = sref[m * 4 + 0];
        float4 r1 = sref[m * 4 + 1];
        float4 r2 = sref[m * 4 + 2];
        float4 r3 = sref[m * 4 + 3];
        float dot = x0.x*r0.x + x0.y*r0.y + x0.z*r0.z + x0.w*r0.w
                  + x1.x*r1.x + x1.y*r1.y + x1.z*r1.z + x1.w*r1.w
                  + x2.x*r2.x + x2.y*r2.y + x2.z*r2.z + x2.w*r2.w
                  + x3.x*r3.x + x3.y*r3.y + x3.z*r3.z + x3.w*r3.w;
        float tm = (2.0f * HARDNESS) * dot + sbias[m];
        t[m] = tm;
        tmax = fmaxf(tmax, tm);
    }

    // Pass 2: softmax weights + weighted codeword sum
    float denom = 0.0f;
    float4 z0 = {0,0,0,0}, z1 = {0,0,0,0}, z2 = {0,0,0,0}, z3 = {0,0,0,0};
#pragma unroll
    for (int m = 0; m < CB_M; ++m) {
        float e = __expf(t[m] - tmax);
        denom += e;
        float4 r0 = sref[m * 4 + 0];
        float4 r1 = sref[m * 4 + 1];
        float4 r2 = sref[m * 4 + 2];
        float4 r3 = sref[m * 4 + 3];
        z0.x += e * r0.x; z0.y += e * r0.y; z0.z += e * r0.z; z0.w += e * r0.w;
        z1.x += e * r1.x; z1.y += e * r1.y; z1.z += e * r1.z; z1.w += e * r1.w;
        z2.x += e * r2.x; z2.y += e * r2.y; z2.z += e * r2.z; z2.w += e * r2.w;
        z3.x += e * r3.x; z3.y += e * r3.y; z3.z += e * r3.z; z3.w += e * r3.w;
    }

    float inv = 1.0f / denom;
    z0.x *= inv; z0.y *= inv; z0.z *= inv; z0.w *= inv;
    z1.x *= inv; z1.y *= inv; z1.z *= inv; z1.w *= inv;
    z2.x *= inv; z2.y *= inv; z2.z *= inv; z2.w *= inv;
    z3.x *= inv; z3.y *= inv; z3.z *= inv; z3.w *= inv;

    float4* op = (float4*)(out + (size_t)i * CB_D);
    op[0] = z0; op[1] = z1; op[2] = z2; op[3] = z3;
}

extern "C" void kernel_launch(void* const* d_in, const int* in_sizes, int n_in,
                              void* d_out, int out_size, void* d_ws, size_t ws_size,
                              hipStream_t stream) {
    const float* x   = (const float*)d_in[0];   // (64,8,32,32,16) f32
    const float* ref = (const float*)d_in[1];   // (64,16) f32
    float* out = (float*)d_out;

    const int nvec = in_sizes[0] / CB_D;        // 524288
    const int block = 256;
    const int grid = (nvec + block - 1) / block;
    stq_kernel<<<grid, block, 0, stream>>>(x, ref, out, nvec);
}

// Round 2
// 159.514 us; speedup vs baseline: 1.1596x; 1.1596x over previous
//
#include <hip/hip_runtime.h>
#include <hip/hip_bf16.h>
#include <math.h>

#define CB_M 64      // codewords
#define CB_D 16      // vector dim
#define HARDNESS 5.0f

__global__ __launch_bounds__(256, 4) void stq_kernel(const float* __restrict__ x,
                                                     const float* __restrict__ ref,
                                                     float* __restrict__ out,
                                                     int nvec) {
    // LDS codebook, pre-scaled by 2H. sbias[m] = -H*||r_m||^2.
    // t_m = x . (2H r_m) + bias_m = 2H (x.r_m) - H ||r_m||^2  (x^2 cancels in softmax)
    __shared__ float4 srefs[CB_M * 4];
    __shared__ float  sbias[CB_M];

    const int tid = threadIdx.x;
    if (tid < CB_M) {
        const float4* rp = (const float4*)(ref + tid * CB_D);
        float4 a = rp[0], b = rp[1], c = rp[2], d = rp[3];
        float r2 = a.x*a.x + a.y*a.y + a.z*a.z + a.w*a.w
                 + b.x*b.x + b.y*b.y + b.z*b.z + b.w*b.w
                 + c.x*c.x + c.y*c.y + c.z*c.z + c.w*c.w
                 + d.x*d.x + d.y*d.y + d.z*d.z + d.w*d.w;
        sbias[tid] = -HARDNESS * r2;
        const float s = 2.0f * HARDNESS;
        srefs[tid*4+0] = make_float4(a.x*s, a.y*s, a.z*s, a.w*s);
        srefs[tid*4+1] = make_float4(b.x*s, b.y*s, b.z*s, b.w*s);
        srefs[tid*4+2] = make_float4(c.x*s, c.y*s, c.z*s, c.w*s);
        srefs[tid*4+3] = make_float4(d.x*s, d.y*s, d.z*s, d.w*s);
    }
    __syncthreads();

    const int i = blockIdx.x * blockDim.x + tid;
    if (i >= nvec) return;

    const float4* xp = (const float4*)(x + (size_t)i * CB_D);
    float4 x0 = xp[0], x1 = xp[1], x2 = xp[2], x3 = xp[3];

    // Pass 1: running max of t_m only (no t[] array -> low VGPR count)
    float tmax = -INFINITY;
#pragma unroll
    for (int m = 0; m < CB_M; ++m) {
        float4 r0 = srefs[m*4+0];
        float4 r1 = srefs[m*4+1];
        float4 r2 = srefs[m*4+2];
        float4 r3 = srefs[m*4+3];
        float t = sbias[m]
                + x0.x*r0.x + x0.y*r0.y + x0.z*r0.z + x0.w*r0.w
                + x1.x*r1.x + x1.y*r1.y + x1.z*r1.z + x1.w*r1.w
                + x2.x*r2.x + x2.y*r2.y + x2.z*r2.z + x2.w*r2.w
                + x3.x*r3.x + x3.y*r3.y + x3.z*r3.z + x3.w*r3.w;
        tmax = fmaxf(tmax, t);
    }

    // Pass 2: recompute t_m, softmax weight, accumulate z = sum e * (2H r)
    float denom = 0.0f;
    float4 z0 = {0,0,0,0}, z1 = {0,0,0,0}, z2 = {0,0,0,0}, z3 = {0,0,0,0};
#pragma unroll
    for (int m = 0; m < CB_M; ++m) {
        float4 r0 = srefs[m*4+0];
        float4 r1 = srefs[m*4+1];
        float4 r2 = srefs[m*4+2];
        float4 r3 = srefs[m*4+3];
        float t = sbias[m] - tmax
                + x0.x*r0.x + x0.y*r0.y + x0.z*r0.z + x0.w*r0.w
                + x1.x*r1.x + x1.y*r1.y + x1.z*r1.z + x1.w*r1.w
                + x2.x*r2.x + x2.y*r2.y + x2.z*r2.z + x2.w*r2.w
                + x3.x*r3.x + x3.y*r3.y + x3.z*r3.z + x3.w*r3.w;
        float e = __expf(t);
        denom += e;
        z0.x += e * r0.x; z0.y += e * r0.y; z0.z += e * r0.z; z0.w += e * r0.w;
        z1.x += e * r1.x; z1.y += e * r1.y; z1.z += e * r1.z; z1.w += e * r1.w;
        z2.x += e * r2.x; z2.y += e * r2.y; z2.z += e * r2.z; z2.w += e * r2.w;
        z3.x += e * r3.x; z3.y += e * r3.y; z3.z += e * r3.z; z3.w += e * r3.w;
    }

    // z currently holds sum e * (2H r); true output = z / (2H * denom)
    float inv = 1.0f / ((2.0f * HARDNESS) * denom);
    z0.x *= inv; z0.y *= inv; z0.z *= inv; z0.w *= inv;
    z1.x *= inv; z1.y *= inv; z1.z *= inv; z1.w *= inv;
    z2.x *= inv; z2.y *= inv; z2.z *= inv; z2.w *= inv;
    z3.x *= inv; z3.y *= inv; z3.z *= inv; z3.w *= inv;

    float4* op = (float4*)(out + (size_t)i * CB_D);
    op[0] = z0; op[1] = z1; op[2] = z2; op[3] = z3;
}

extern "C" void kernel_launch(void* const* d_in, const int* in_sizes, int n_in,
                              void* d_out, int out_size, void* d_ws, size_t ws_size,
                              hipStream_t stream) {
    const float* x   = (const float*)d_in[0];   // (64,8,32,32,16) f32
    const float* ref = (const float*)d_in[1];   // (64,16) f32
    float* out = (float*)d_out;

    const int nvec = in_sizes[0] / CB_D;        // 524288
    const int block = 256;
    const int grid = (nvec + block - 1) / block;
    stq_kernel<<<grid, block, 0, stream>>>(x, ref, out, nvec);
}

// Round 3
// 123.503 us; speedup vs baseline: 1.4978x; 1.2916x over previous
//
#include <hip/hip_runtime.h>
#include <hip/hip_bf16.h>
#include <math.h>

#define CB_M 64      // codewords
#define CB_D 16      // vector dim
#define HARD 5.0f

// Each thread handles TWO consecutive vectors (A, B). Single-pass online
// softmax: no t[] array (low VGPR), one sweep over the codebook (half the
// LDS reads of 2-pass), and each codeword LDS read amortized over 2 vectors.
__global__ __launch_bounds__(256, 2) void stq_kernel(const float* __restrict__ x,
                                                     const float* __restrict__ ref,
                                                     float* __restrict__ out,
                                                     int npair) {
    // Codebook pre-scaled by 2H; bias = -H*||r||^2. t = x.(2H r) - H||r||^2
    // (the ||x||^2 term cancels in the softmax).
    __shared__ float4 srefs[CB_M * 4];
    __shared__ float  sbias[CB_M];

    const int tid = threadIdx.x;
    if (tid < CB_M) {
        const float4* rp = (const float4*)(ref + tid * CB_D);
        float4 a = rp[0], b = rp[1], c = rp[2], d = rp[3];
        float r2 = a.x*a.x + a.y*a.y + a.z*a.z + a.w*a.w
                 + b.x*b.x + b.y*b.y + b.z*b.z + b.w*b.w
                 + c.x*c.x + c.y*c.y + c.z*c.z + c.w*c.w
                 + d.x*d.x + d.y*d.y + d.z*d.z + d.w*d.w;
        sbias[tid] = -HARD * r2;
        const float s = 2.0f * HARD;
        srefs[tid*4+0] = make_float4(a.x*s, a.y*s, a.z*s, a.w*s);
        srefs[tid*4+1] = make_float4(b.x*s, b.y*s, b.z*s, b.w*s);
        srefs[tid*4+2] = make_float4(c.x*s, c.y*s, c.z*s, c.w*s);
        srefs[tid*4+3] = make_float4(d.x*s, d.y*s, d.z*s, d.w*s);
    }
    __syncthreads();

    const int p = blockIdx.x * blockDim.x + tid;
    if (p >= npair) return;

    const float4* xp = (const float4*)(x + (size_t)p * (2 * CB_D));
    float4 a0 = xp[0], a1 = xp[1], a2 = xp[2], a3 = xp[3];   // vector A
    float4 b0 = xp[4], b1 = xp[5], b2 = xp[6], b3 = xp[7];   // vector B

    float tmaxA = -INFINITY, tmaxB = -INFINITY;
    float denA = 0.0f, denB = 0.0f;
    float4 zA0 = {0,0,0,0}, zA1 = {0,0,0,0}, zA2 = {0,0,0,0}, zA3 = {0,0,0,0};
    float4 zB0 = {0,0,0,0}, zB1 = {0,0,0,0}, zB2 = {0,0,0,0}, zB3 = {0,0,0,0};

#pragma unroll 4
    for (int m = 0; m < CB_M; ++m) {
        float4 r0 = srefs[m*4+0];
        float4 r1 = srefs[m*4+1];
        float4 r2 = srefs[m*4+2];
        float4 r3 = srefs[m*4+3];
        float bias = sbias[m];

        float tA = bias
                 + a0.x*r0.x + a0.y*r0.y + a0.z*r0.z + a0.w*r0.w
                 + a1.x*r1.x + a1.y*r1.y + a1.z*r1.z + a1.w*r1.w
                 + a2.x*r2.x + a2.y*r2.y + a2.z*r2.z + a2.w*r2.w
                 + a3.x*r3.x + a3.y*r3.y + a3.z*r3.z + a3.w*r3.w;
        float tB = bias
                 + b0.x*r0.x + b0.y*r0.y + b0.z*r0.z + b0.w*r0.w
                 + b1.x*r1.x + b1.y*r1.y + b1.z*r1.z + b1.w*r1.w
                 + b2.x*r2.x + b2.y*r2.y + b2.z*r2.z + b2.w*r2.w
                 + b3.x*r3.x + b3.y*r3.y + b3.z*r3.z + b3.w*r3.w;

        // online softmax update, vector A
        float nmA = fmaxf(tmaxA, tA);
        float alA = __expf(tmaxA - nmA);     // exp(-inf)=0 on first iter
        float eA  = __expf(tA - nmA);
        tmaxA = nmA;
        denA = denA * alA + eA;
        zA0.x = zA0.x*alA + eA*r0.x; zA0.y = zA0.y*alA + eA*r0.y;
        zA0.z = zA0.z*alA + eA*r0.z; zA0.w = zA0.w*alA + eA*r0.w;
        zA1.x = zA1.x*alA + eA*r1.x; zA1.y = zA1.y*alA + eA*r1.y;
        zA1.z = zA1.z*alA + eA*r1.z; zA1.w = zA1.w*alA + eA*r1.w;
        zA2.x = zA2.x*alA + eA*r2.x; zA2.y = zA2.y*alA + eA*r2.y;
        zA2.z = zA2.z*alA + eA*r2.z; zA2.w = zA2.w*alA + eA*r2.w;
        zA3.x = zA3.x*alA + eA*r3.x; zA3.y = zA3.y*alA + eA*r3.y;
        zA3.z = zA3.z*alA + eA*r3.z; zA3.w = zA3.w*alA + eA*r3.w;

        // online softmax update, vector B
        float nmB = fmaxf(tmaxB, tB);
        float alB = __expf(tmaxB - nmB);
        float eB  = __expf(tB - nmB);
        tmaxB = nmB;
        denB = denB * alB + eB;
        zB0.x = zB0.x*alB + eB*r0.x; zB0.y = zB0.y*alB + eB*r0.y;
        zB0.z = zB0.z*alB + eB*r0.z; zB0.w = zB0.w*alB + eB*r0.w;
        zB1.x = zB1.x*alB + eB*r1.x; zB1.y = zB1.y*alB + eB*r1.y;
        zB1.z = zB1.z*alB + eB*r1.z; zB1.w = zB1.w*alB + eB*r1.w;
        zB2.x = zB2.x*alB + eB*r2.x; zB2.y = zB2.y*alB + eB*r2.y;
        zB2.z = zB2.z*alB + eB*r2.z; zB2.w = zB2.w*alB + eB*r2.w;
        zB3.x = zB3.x*alB + eB*r3.x; zB3.y = zB3.y*alB + eB*r3.y;
        zB3.z = zB3.z*alB + eB*r3.z; zB3.w = zB3.w*alB + eB*r3.w;
    }

    // z holds sum e*(2H r); divide by 2H*denom
    float invA = 1.0f / ((2.0f * HARD) * denA);
    float invB = 1.0f / ((2.0f * HARD) * denB);

    float4* op = (float4*)(out + (size_t)p * (2 * CB_D));
    op[0] = make_float4(zA0.x*invA, zA0.y*invA, zA0.z*invA, zA0.w*invA);
    op[1] = make_float4(zA1.x*invA, zA1.y*invA, zA1.z*invA, zA1.w*invA);
    op[2] = make_float4(zA2.x*invA, zA2.y*invA, zA2.z*invA, zA2.w*invA);
    op[3] = make_float4(zA3.x*invA, zA3.y*invA, zA3.z*invA, zA3.w*invA);
    op[4] = make_float4(zB0.x*invB, zB0.y*invB, zB0.z*invB, zB0.w*invB);
    op[5] = make_float4(zB1.x*invB, zB1.y*invB, zB1.z*invB, zB1.w*invB);
    op[6] = make_float4(zB2.x*invB, zB2.y*invB, zB2.z*invB, zB2.w*invB);
    op[7] = make_float4(zB3.x*invB, zB3.y*invB, zB3.z*invB, zB3.w*invB);
}

extern "C" void kernel_launch(void* const* d_in, const int* in_sizes, int n_in,
                              void* d_out, int out_size, void* d_ws, size_t ws_size,
                              hipStream_t stream) {
    const float* x   = (const float*)d_in[0];   // (64,8,32,32,16) f32
    const float* ref = (const float*)d_in[1];   // (64,16) f32
    float* out = (float*)d_out;

    const int nvec  = in_sizes[0] / CB_D;       // 524288
    const int npair = nvec / 2;                 // 262144
    const int block = 256;
    const int grid  = (npair + block - 1) / block;
    stq_kernel<<<grid, block, 0, stream>>>(x, ref, out, npair);
}